// Round 11
// baseline (151.434 us; speedup 1.0000x reference)
//
#include <hip/hip_runtime.h>

// ---------------------------------------------------------------------------
// MultiheadSelfAttention: x[2,2048,1024] f32, w_qkv[3072,1024] f32,
// w_out[1024,1024] f32 -> out[2,2048,1024] f32.
// cast->bf16, qkv = x @ w_qkv^T (MFMA), V pre-transpose, causal flash attn
// (single-wave blocks, 32-row band, 32-key tiles, 32x32 MFMA swapped ops,
// in-register softmax, permlane32_swap P redistribution, O^T accumulation,
// barrier-free double-buffered K/V with counted vmcnt, LPT dispatch order),
// out = ctx @ w_out^T. fp32 accumulation.
// ---------------------------------------------------------------------------

typedef short short8 __attribute__((ext_vector_type(8)));
typedef float f32x4 __attribute__((ext_vector_type(4)));
typedef float f32x16 __attribute__((ext_vector_type(16)));
typedef unsigned int u32x2 __attribute__((ext_vector_type(2)));
typedef unsigned short u16;
typedef unsigned int u32;

#define T_SEQ 2048
#define N_B 2
#define N_H 16
#define HD 64
#define DM 1024
#define TRIPLE 3072

__device__ __forceinline__ u16 f2bf(float f) {
  union { float f; unsigned u; } v;
  v.f = f;
  unsigned r = v.u + 0x7fffu + ((v.u >> 16) & 1u);
  return (u16)(r >> 16);
}

__device__ __forceinline__ float bf2f(u16 x) {
  return __uint_as_float((u32)x << 16);
}

__device__ __forceinline__ u32 cvtpk(float a, float b) {
  u32 r;
  asm("v_cvt_pk_bf16_f32 %0, %1, %2" : "=v"(r) : "v"(a), "v"(b));
  return r;
}

// SSA-safe permlane32_swap
__device__ __forceinline__ void pl32swap(u32& a, u32& b) {
  u32x2 r = __builtin_amdgcn_permlane32_swap(a, b, false, false);
  a = r[0];
  b = r[1];
}

typedef const __attribute__((address_space(1))) void gvoid;
typedef __attribute__((address_space(3))) void lvoid;

__device__ __forceinline__ void g2l16(const void* g, void* l) {
  __builtin_amdgcn_global_load_lds((gvoid*)g, (lvoid*)l, 16, 0, 0);
}

__device__ __forceinline__ void storeC(float* p, float v) { *p = v; }
__device__ __forceinline__ void storeC(u16* p, float v) { *p = f2bf(v); }

// ---------------------------------------------------------------------------
__global__ __launch_bounds__(256) void cast_all(const float4* __restrict__ x,
                                                const float4* __restrict__ wq,
                                                const float4* __restrict__ wo,
                                                ushort4* __restrict__ out) {
  int i = blockIdx.x * 256 + threadIdx.x;
  const float4* src;
  int off;
  if (i < 1048576) { src = x; off = 0; }
  else if (i < 1835008) { src = wq; off = 1048576; }
  else { src = wo; off = 1835008; }
  float4 v = src[i - off];
  ushort4 o;
  o.x = f2bf(v.x); o.y = f2bf(v.y); o.z = f2bf(v.z); o.w = f2bf(v.w);
  out[i] = o;
}

// ---------------------------------------------------------------------------
// V transpose: qkv[b*T+t][2048 + h*64 + d] -> vT[(b*16+h)*64 + d][t] (bf16).
// ---------------------------------------------------------------------------
__global__ __launch_bounds__(256) void vtrans(const u16* __restrict__ qkv,
                                              u16* __restrict__ vT) {
  const int tid = threadIdx.x;
  const int w = tid >> 6, lane = tid & 63;
  const int ti = lane >> 3, di = lane & 7;
  const int h = blockIdx.y, b = blockIdx.z;
  const int t0 = blockIdx.x * 256 + w * 64 + ti * 8;

  const u16* src = qkv + (size_t)(b * T_SEQ + t0) * TRIPLE + 2 * DM + h * HD + di * 8;
  u32 x[8][4];
#pragma unroll
  for (int e = 0; e < 8; ++e) {
    union { short8 v; u32 u[4]; } cv;
    cv.v = *(const short8*)(src + (size_t)e * TRIPLE);
#pragma unroll
    for (int j = 0; j < 4; ++j) x[e][j] = cv.u[j];
  }
  u32 y[8][4];
#pragma unroll
  for (int a = 0; a < 4; ++a)
#pragma unroll
    for (int j = 0; j < 4; ++j) {
      u32 lo = x[2 * a][j], hi = x[2 * a + 1][j];
      y[2 * a][j] = (lo & 0x0000FFFFu) | (hi << 16);
      y[2 * a + 1][j] = (lo >> 16) | (hi & 0xFFFF0000u);
    }
  u16* dst = vT + ((size_t)(b * N_H + h) * HD + di * 8) * T_SEQ + t0;
#pragma unroll
  for (int dd = 0; dd < 8; ++dd) {
    union { short8 v; u32 u[4]; } cv;
#pragma unroll
    for (int a = 0; a < 4; ++a) cv.u[a] = y[2 * a + (dd & 1)][dd >> 1];
    *(short8*)(dst + (size_t)dd * T_SEQ) = cv.v;
  }
}

// ---------------------------------------------------------------------------
// C[M][N] = A[M][K] * W[N][K]^T  (bf16 in, fp32 acc). 128x128 tile, BK=64.
// ---------------------------------------------------------------------------
template <typename OutT>
__global__ __launch_bounds__(256) void gemm_bt(const u16* __restrict__ A,
                                               const u16* __restrict__ W,
                                               OutT* __restrict__ C,
                                               int M, int N, int K) {
  __shared__ char As[128 * 64 * 2];
  __shared__ char Bs[128 * 64 * 2];
  const int tid = threadIdx.x;
  const int lane = tid & 63, w = tid >> 6;
  const int l15 = lane & 15, l4 = lane >> 4;
  const int m0 = blockIdx.y * 128, n0 = blockIdx.x * 128;
  const int wr = (w >> 1) * 64, wc = (w & 1) * 64;

  const f32x4 zero = {0.f, 0.f, 0.f, 0.f};
  f32x4 acc[4][4];
#pragma unroll
  for (int m = 0; m < 4; ++m)
#pragma unroll
    for (int n = 0; n < 4; ++n) acc[m][n] = zero;

  for (int k0 = 0; k0 < K; k0 += 64) {
#pragma unroll
    for (int i = 0; i < 4; ++i) {
      const int cb = (i * 4 + w) * 64;
      const int c = cb + lane;
      const int row = c >> 3;
      const int ks = ((c & 7) ^ (row & 7)) * 8;
      g2l16(A + (size_t)(m0 + row) * K + k0 + ks, As + (size_t)cb * 16);
      g2l16(W + (size_t)(n0 + row) * K + k0 + ks, Bs + (size_t)cb * 16);
    }
    __syncthreads();

#pragma unroll
    for (int kk = 0; kk < 2; ++kk) {
      short8 a[4], b[4];
#pragma unroll
      for (int m = 0; m < 4; ++m) {
        int row = wr + m * 16 + l15;
        int slot = (kk * 4 + l4) ^ (row & 7);
        a[m] = *(const short8*)(As + row * 128 + slot * 16);
      }
#pragma unroll
      for (int n = 0; n < 4; ++n) {
        int row = wc + n * 16 + l15;
        int slot = (kk * 4 + l4) ^ (row & 7);
        b[n] = *(const short8*)(Bs + row * 128 + slot * 16);
      }
#pragma unroll
      for (int m = 0; m < 4; ++m)
#pragma unroll
        for (int n = 0; n < 4; ++n)
          acc[m][n] = __builtin_amdgcn_mfma_f32_16x16x32_bf16(a[m], b[n], acc[m][n], 0, 0, 0);
    }
    __syncthreads();
  }

#pragma unroll
  for (int m = 0; m < 4; ++m)
#pragma unroll
    for (int n = 0; n < 4; ++n)
#pragma unroll
      for (int r = 0; r < 4; ++r) {
        int row = m0 + wr + m * 16 + l4 * 4 + r;
        int col = n0 + wc + n * 16 + l15;
        storeC(C + (size_t)row * N + col, acc[m][n][r]);
      }
}

// ---------------------------------------------------------------------------
// Causal flash attention: SINGLE-WAVE blocks (64 threads), barrier-free.
// Block = one 32-row q-band "band" of one (b,h); tiles of 32 keys,
// kt = 0..band (diag last). Double-buffered K/V staged by global_load_lds;
// stage(t+1) issued at loop top, counted s_waitcnt vmcnt(8) before compute.
// Grid (32 bh, 64 bands), band = 63 - blockIdx.y -> longest blocks dispatch
// first (LPT); bh on XCD g%8 (L2 holds 4 heads' full K/V = 2 MB/XCD).
// Softmax in-register (q = lane&31); P->PV-B-frag via cvt_pk+permlane32_swap;
// O accumulated transposed (O^T[d][q]).
// ---------------------------------------------------------------------------
__global__ __launch_bounds__(64) void attn_fwd(const u16* __restrict__ qkv,
                                               const u16* __restrict__ vT,
                                               u16* __restrict__ ctx) {
  __shared__ char Ks[2][4096];   // K tile [32 key][8 slots x16B], slot=j^(key&7)
  __shared__ char Vs[2][4096];   // V^T tile [64 d][4 slots x16B], slot=j^(d&3)

  const int lane = threadIdx.x;                   // 0..63
  const int l31 = lane & 31, hi = lane >> 5;
  const int g = blockIdx.x;                       // b*16+h (XCD colocation)
  const int band = 63 - blockIdx.y;               // LPT: longest first
  const int h = g & 15, b = g >> 4;
  const int q0 = 32 * band;
  const int qrow = q0 + l31;

  // ---- preload Q (B-frag), prescaled by 0.125*log2(e) ----
  const float c_log2 = 0.18033688011112042f;
  short8 qa[4];
  {
    const u16* qp = qkv + (size_t)(b * T_SEQ + qrow) * TRIPLE + h * HD + hi * 8;
#pragma unroll
    for (int kst = 0; kst < 4; ++kst) {
      short8 raw = *(const short8*)(qp + kst * 16);
      union { short8 v; u32 w4[4]; } qq;
#pragma unroll
      for (int j = 0; j < 4; ++j)
        qq.w4[j] = cvtpk(bf2f((u16)raw[2 * j]) * c_log2,
                         bf2f((u16)raw[2 * j + 1]) * c_log2);
      qa[kst] = qq.v;
    }
  }

  // ---- staging bases (pre-swizzled source, linear LDS dest) ----
  // K: chunk c = i*64+lane; key-row = i*8 + (lane>>3); src k-chunk = (lane&7)^(row&7)
  const int kr0 = lane >> 3;
  const int swzk = ((lane & 7) ^ kr0) << 3;
  const u16* kbase = qkv + (size_t)(b * T_SEQ + kr0) * TRIPLE + DM + h * HD + swzk;
  // V: chunk c = i*64+lane; d-row = i*16 + (lane>>2); src key-chunk = (lane&3)^(d&3)
  const int vd0 = lane >> 2;
  const int swzv = ((lane & 3) ^ (vd0 & 3)) << 3;
  const u16* vbase = vT + ((size_t)g * HD + vd0) * T_SEQ + swzv;

#define STAGE(kt_, buf_)                                                        \
  {                                                                             \
    _Pragma("unroll") for (int i_ = 0; i_ < 4; ++i_) {                          \
      g2l16(kbase + (size_t)((kt_) * 32 + 8 * i_) * TRIPLE,                     \
            Ks[buf_] + lane * 16 + 1024 * i_);                                  \
      g2l16(vbase + (size_t)(16 * i_) * T_SEQ + (kt_) * 32,                     \
            Vs[buf_] + lane * 16 + 1024 * i_);                                  \
    }                                                                           \
  }

  const f32x16 zero16 = {0,0,0,0,0,0,0,0,0,0,0,0,0,0,0,0};
  f32x16 o[2];
  o[0] = zero16; o[1] = zero16;
  float mr = -INFINITY, lr = 0.f;

  // ---- prologue ----
  STAGE(0, 0);

  for (int t = 0;; ++t) {
    const int cur = t & 1;

    // issue next tile's loads, then wait (counted) for the current tile
    if (t < band) {
      STAGE(t + 1, cur ^ 1);
      asm volatile("s_waitcnt vmcnt(8)" ::: "memory");
    } else {
      asm volatile("s_waitcnt vmcnt(0)" ::: "memory");
    }

    // ---- S^T = mfma(K, Q): lane holds S[key=(r&3)+8(r>>2)+4hi][q=l31] ----
    f32x16 s = zero16;
    __builtin_amdgcn_s_setprio(1);
#pragma unroll
    for (int kst = 0; kst < 4; ++kst) {
      const int slot = ((kst * 2 + hi) ^ (l31 & 7)) << 4;
      short8 kf = *(const short8*)(Ks[cur] + l31 * 128 + slot);
      s = __builtin_amdgcn_mfma_f32_32x32x16_bf16(kf, qa[kst], s, 0, 0, 0);
    }
    __builtin_amdgcn_s_setprio(0);

    // ---- causal mask on the diagonal tile ----
    if (t == band) {
      const int kb0 = t * 32 + 4 * hi;
#pragma unroll
      for (int r = 0; r < 16; ++r) {
        const int key = kb0 + (r & 3) + 8 * (r >> 2);
        if (key > qrow) s[r] = -INFINITY;
      }
    }

    // ---- in-register online softmax (row q = l31), defer-max THR=8 ----
    float tA = s[0], tB = s[1], tC = s[2], tD = s[3];
#pragma unroll
    for (int r = 4; r < 16; r += 4) {
      tA = fmaxf(tA, s[r]);
      tB = fmaxf(tB, s[r + 1]);
      tC = fmaxf(tC, s[r + 2]);
      tD = fmaxf(tD, s[r + 3]);
    }
    float mx = fmaxf(fmaxf(tA, tB), fmaxf(tC, tD));
    mx = fmaxf(mx, __shfl_xor(mx, 32));   // lane^32 shares q
    if (!__all(mx - mr <= 8.0f)) {
      const float mn = fmaxf(mr, mx);
      const float fr = exp2f(mr - mn);    // 0 on first tile
      lr *= fr;
#pragma unroll
      for (int r = 0; r < 16; ++r) { o[0][r] *= fr; o[1][r] *= fr; }
      mr = mn;
    }
    {
      float pA = 0.f, pB = 0.f, pC = 0.f, pD = 0.f;
#pragma unroll
      for (int r = 0; r < 16; r += 4) {
        s[r] = exp2f(s[r] - mr); pA += s[r];
        s[r + 1] = exp2f(s[r + 1] - mr); pB += s[r + 1];
        s[r + 2] = exp2f(s[r + 2] - mr); pC += s[r + 2];
        s[r + 3] = exp2f(s[r + 3] - mr); pD += s[r + 3];
      }
      lr += (pA + pB) + (pC + pD);        // per-lane partial (own 32 keys)
    }

    // ---- P -> PV B-fragments (cvt_pk + permlane32_swap), PV MFMA ----
    __builtin_amdgcn_s_setprio(1);
#pragma unroll
    for (int sub = 0; sub < 2; ++sub) {
      const int base = 8 * sub;
      u32 w00 = cvtpk(s[base + 0], s[base + 1]);
      u32 w01 = cvtpk(s[base + 2], s[base + 3]);
      u32 w10 = cvtpk(s[base + 4], s[base + 5]);
      u32 w11 = cvtpk(s[base + 6], s[base + 7]);
      pl32swap(w00, w10);
      pl32swap(w01, w11);
      union { u32 u[4]; short8 v; } pw;
      pw.u[0] = w00; pw.u[1] = w01; pw.u[2] = w10; pw.u[3] = w11;
      const int vslot = ((sub * 2 + hi) ^ (l31 & 3)) << 4;
      short8 v0 = *(const short8*)(Vs[cur] + l31 * 64 + vslot);
      o[0] = __builtin_amdgcn_mfma_f32_32x32x16_bf16(v0, pw.v, o[0], 0, 0, 0);
      short8 v1 = *(const short8*)(Vs[cur] + (32 + l31) * 64 + vslot);
      o[1] = __builtin_amdgcn_mfma_f32_32x32x16_bf16(v1, pw.v, o[1], 0, 0, 0);
    }
    __builtin_amdgcn_s_setprio(0);

    if (t == band) break;
  }

  // ---- epilogue: write O^T (q = l31 per-lane) ----
  lr += __shfl_xor(lr, 32);
  const float inv = __builtin_amdgcn_rcpf(lr);
  u16* crow = ctx + (size_t)(b * T_SEQ + qrow) * DM + h * HD;
#pragma unroll
  for (int df = 0; df < 2; ++df)
#pragma unroll
    for (int r = 0; r < 16; r += 2) {
      const int d = df * 32 + (r & 3) + 8 * (r >> 2) + 4 * hi;
      u32 pk = cvtpk(o[df][r] * inv, o[df][r + 1] * inv);
      *(u32*)(crow + d) = pk;
    }
#undef STAGE
}

// ---------------------------------------------------------------------------
extern "C" void kernel_launch(void* const* d_in, const int* in_sizes, int n_in,
                              void* d_out, int out_size, void* d_ws, size_t ws_size,
                              hipStream_t stream) {
  const float* x = (const float*)d_in[0];
  const float* wqkv = (const float*)d_in[1];
  const float* wout = (const float*)d_in[2];
  float* out = (float*)d_out;
  char* ws = (char*)d_ws;

  u16* xb    = (u16*)(ws);                       //  8 MB
  u16* wqkvb = (u16*)(ws + 8u * 1024 * 1024);    //  6 MB
  u16* woutb = (u16*)(ws + 14u * 1024 * 1024);   //  2 MB
  u16* qkvb  = (u16*)(ws + 16u * 1024 * 1024);   // 24 MB
  u16* ctxb  = (u16*)(ws + 40u * 1024 * 1024);   //  8 MB
  u16* vTb   = (u16*)(ws + 48u * 1024 * 1024);   //  8 MB

  cast_all<<<8192, 256, 0, stream>>>((const float4*)x, (const float4*)wqkv,
                                     (const float4*)wout, (ushort4*)xb);

  gemm_bt<u16><<<dim3(24, 32), 256, 0, stream>>>(xb, wqkvb, qkvb, 4096, 3072, 1024);

  vtrans<<<dim3(8, N_H, N_B), 256, 0, stream>>>(qkvb, vTb);

  attn_fwd<<<dim3(32, 64), 64, 0, stream>>>(qkvb, vTb, ctxb);

  gemm_bt<float><<<dim3(8, 32), 256, 0, stream>>>(ctxb, woutb, out, 4096, 1024, 1024);
}

// Round 12
// 130.168 us; speedup vs baseline: 1.1634x; 1.1634x over previous
//
#include <hip/hip_runtime.h>

// ---------------------------------------------------------------------------
// MultiheadSelfAttention: x[2,2048,1024] f32, w_qkv[3072,1024] f32,
// w_out[1024,1024] f32 -> out[2,2048,1024] f32.
// cast->bf16, qkv = x @ w_qkv^T (MFMA), V pre-transpose, causal flash attn
// (4-wave 64-row blocks, paired q-bands (p,31-p), pass B diag-first descending,
// TRIPLE-buffered K/V via global_load_lds + counted vmcnt, XCD-colocated,
// 2 independent blocks/CU), out = ctx @ w_out^T. fp32 accumulation.
// ---------------------------------------------------------------------------

typedef short short8 __attribute__((ext_vector_type(8)));
typedef float f32x4 __attribute__((ext_vector_type(4)));
typedef unsigned short u16;
typedef unsigned int u32;

#define T_SEQ 2048
#define N_B 2
#define N_H 16
#define HD 64
#define DM 1024
#define TRIPLE 3072

__device__ __forceinline__ u16 f2bf(float f) {
  union { float f; unsigned u; } v;
  v.f = f;
  unsigned r = v.u + 0x7fffu + ((v.u >> 16) & 1u);
  return (u16)(r >> 16);
}

__device__ __forceinline__ float bf2f(u16 x) {
  return __uint_as_float((u32)x << 16);
}

__device__ __forceinline__ u32 cvtpk(float a, float b) {
  u32 r;
  asm("v_cvt_pk_bf16_f32 %0, %1, %2" : "=v"(r) : "v"(a), "v"(b));
  return r;
}

typedef const __attribute__((address_space(1))) void gvoid;
typedef __attribute__((address_space(3))) void lvoid;

__device__ __forceinline__ void g2l16(const void* g, void* l) {
  __builtin_amdgcn_global_load_lds((gvoid*)g, (lvoid*)l, 16, 0, 0);
}

__device__ __forceinline__ void storeC(float* p, float v) { *p = v; }
__device__ __forceinline__ void storeC(u16* p, float v) { *p = f2bf(v); }

// ---------------------------------------------------------------------------
// fused cast of x | w_qkv | w_out into contiguous bf16 workspace
__global__ __launch_bounds__(256) void cast_all(const float4* __restrict__ x,
                                                const float4* __restrict__ wq,
                                                const float4* __restrict__ wo,
                                                ushort4* __restrict__ out) {
  int i = blockIdx.x * 256 + threadIdx.x;
  const float4* src;
  int off;
  if (i < 1048576) { src = x; off = 0; }
  else if (i < 1835008) { src = wq; off = 1048576; }
  else { src = wo; off = 1835008; }
  float4 v = src[i - off];
  ushort4 o;
  o.x = f2bf(v.x); o.y = f2bf(v.y); o.z = f2bf(v.z); o.w = f2bf(v.w);
  out[i] = o;
}

// ---------------------------------------------------------------------------
// V transpose: qkv[b*T+t][2048 + h*64 + d] -> vT[(b*16+h)*64 + d][t] (bf16).
// ---------------------------------------------------------------------------
__global__ __launch_bounds__(256) void vtrans(const u16* __restrict__ qkv,
                                              u16* __restrict__ vT) {
  const int tid = threadIdx.x;
  const int w = tid >> 6, lane = tid & 63;
  const int ti = lane >> 3, di = lane & 7;
  const int h = blockIdx.y, b = blockIdx.z;
  const int t0 = blockIdx.x * 256 + w * 64 + ti * 8;

  const u16* src = qkv + (size_t)(b * T_SEQ + t0) * TRIPLE + 2 * DM + h * HD + di * 8;
  u32 x[8][4];
#pragma unroll
  for (int e = 0; e < 8; ++e) {
    union { short8 v; u32 u[4]; } cv;
    cv.v = *(const short8*)(src + (size_t)e * TRIPLE);
#pragma unroll
    for (int j = 0; j < 4; ++j) x[e][j] = cv.u[j];
  }
  u32 y[8][4];
#pragma unroll
  for (int a = 0; a < 4; ++a)
#pragma unroll
    for (int j = 0; j < 4; ++j) {
      u32 lo = x[2 * a][j], hi = x[2 * a + 1][j];
      y[2 * a][j] = (lo & 0x0000FFFFu) | (hi << 16);
      y[2 * a + 1][j] = (lo >> 16) | (hi & 0xFFFF0000u);
    }
  u16* dst = vT + ((size_t)(b * N_H + h) * HD + di * 8) * T_SEQ + t0;
#pragma unroll
  for (int dd = 0; dd < 8; ++dd) {
    union { short8 v; u32 u[4]; } cv;
#pragma unroll
    for (int a = 0; a < 4; ++a) cv.u[a] = y[2 * a + (dd & 1)][dd >> 1];
    *(short8*)(dst + (size_t)dd * T_SEQ) = cv.v;
  }
}

// ---------------------------------------------------------------------------
// C[M][N] = A[M][K] * W[N][K]^T  (bf16 in, fp32 acc). 128x128 tile, BK=64.
// ---------------------------------------------------------------------------
template <typename OutT>
__global__ __launch_bounds__(256) void gemm_bt(const u16* __restrict__ A,
                                               const u16* __restrict__ W,
                                               OutT* __restrict__ C,
                                               int M, int N, int K) {
  __shared__ char As[128 * 64 * 2];
  __shared__ char Bs[128 * 64 * 2];
  const int tid = threadIdx.x;
  const int lane = tid & 63, w = tid >> 6;
  const int l15 = lane & 15, l4 = lane >> 4;
  const int m0 = blockIdx.y * 128, n0 = blockIdx.x * 128;
  const int wr = (w >> 1) * 64, wc = (w & 1) * 64;

  const f32x4 zero = {0.f, 0.f, 0.f, 0.f};
  f32x4 acc[4][4];
#pragma unroll
  for (int m = 0; m < 4; ++m)
#pragma unroll
    for (int n = 0; n < 4; ++n) acc[m][n] = zero;

  for (int k0 = 0; k0 < K; k0 += 64) {
#pragma unroll
    for (int i = 0; i < 4; ++i) {
      const int cb = (i * 4 + w) * 64;
      const int c = cb + lane;
      const int row = c >> 3;
      const int ks = ((c & 7) ^ (row & 7)) * 8;
      g2l16(A + (size_t)(m0 + row) * K + k0 + ks, As + (size_t)cb * 16);
      g2l16(W + (size_t)(n0 + row) * K + k0 + ks, Bs + (size_t)cb * 16);
    }
    __syncthreads();

#pragma unroll
    for (int kk = 0; kk < 2; ++kk) {
      short8 a[4], b[4];
#pragma unroll
      for (int m = 0; m < 4; ++m) {
        int row = wr + m * 16 + l15;
        int slot = (kk * 4 + l4) ^ (row & 7);
        a[m] = *(const short8*)(As + row * 128 + slot * 16);
      }
#pragma unroll
      for (int n = 0; n < 4; ++n) {
        int row = wc + n * 16 + l15;
        int slot = (kk * 4 + l4) ^ (row & 7);
        b[n] = *(const short8*)(Bs + row * 128 + slot * 16);
      }
#pragma unroll
      for (int m = 0; m < 4; ++m)
#pragma unroll
        for (int n = 0; n < 4; ++n)
          acc[m][n] = __builtin_amdgcn_mfma_f32_16x16x32_bf16(a[m], b[n], acc[m][n], 0, 0, 0);
    }
    __syncthreads();
  }

#pragma unroll
  for (int m = 0; m < 4; ++m)
#pragma unroll
    for (int n = 0; n < 4; ++n)
#pragma unroll
      for (int r = 0; r < 4; ++r) {
        int row = m0 + wr + m * 16 + l4 * 4 + r;
        int col = n0 + wc + n * 16 + l15;
        storeC(C + (size_t)row * N + col, acc[m][n][r]);
      }
}

// ---------------------------------------------------------------------------
// Causal flash attention. 4-wave blocks, 64 q-rows per pass, paired q-bands
// (p, 31-p). Pass A: kt = 0..p ascending (diag last). Pass B: kt = 32-i
// descending (diag first). 33 iterations for every block; at step i all
// blocks of a (b,h) read tile i or 32-i. Triple-buffered K/V staged by
// global_load_lds with 2-deep prefetch; barriers use counted vmcnt(4).
// Grid (g=32, p=16): all blocks of head-group g land on XCD g%8; 2 blocks/CU.
// ---------------------------------------------------------------------------
__global__ __launch_bounds__(256) void attn_fwd(const u16* __restrict__ qkv,
                                                const u16* __restrict__ vT,
                                                u16* __restrict__ ctx) {
  __shared__ char Ks[3][8192];   // K tile [64 key][8 slots x 16B], slot=c^(row&7)
  __shared__ char Vs[3][8192];   // V^T tile [64 d][8 slots x 16B], slot=c^(d&7)
  __shared__ char Pl[4][2048];   // per-wave P [16 q][64 key], swizzled

  const int tid = threadIdx.x;
  const int lane = tid & 63, w = tid >> 6;        // 4 waves
  const int l15 = lane & 15, l4 = lane >> 4;
  const int g = blockIdx.x;                       // b*16+h : same-XCD group
  const int p = blockIdx.y;                       // 0..15
  const int h = g & 15, b = g >> 4;
  const int q0A = 64 * p, q0B = 64 * (31 - p);

  // ---- preload Q for BOTH passes, prescaled by 0.125*log2(e) ----
  const float c_log2 = 0.18033688011112042f;
  short8 qa2[2][2];
#pragma unroll
  for (int ps = 0; ps < 2; ++ps) {
    const int qq0 = ps ? q0B : q0A;
    const u16* qp = qkv + (size_t)(b * T_SEQ + qq0 + w * 16 + l15) * TRIPLE + h * HD;
#pragma unroll
    for (int kk = 0; kk < 2; ++kk) {
      short8 raw = *(const short8*)(qp + kk * 32 + l4 * 8);
      union { short8 v; u32 w4[4]; } qq;
#pragma unroll
      for (int j = 0; j < 4; ++j)
        qq.w4[j] = cvtpk(bf2f((u16)raw[2 * j]) * c_log2,
                         bf2f((u16)raw[2 * j + 1]) * c_log2);
      qa2[ps][kk] = qq.v;
    }
  }

  // ---- staging bases (pre-swizzled source, linear LDS dest) ----
  const int r0 = tid >> 3, c0 = tid & 7;          // r0: 0..31
  const int swz = (c0 ^ (r0 & 7)) << 3;
  const u16* kbase = qkv + (size_t)(b * T_SEQ + r0) * TRIPLE + DM + h * HD + swz;
  const u16* vbase = vT + ((size_t)g * HD + r0) * T_SEQ + swz;

#define STAGE(kt_, buf_)                                                        \
  {                                                                             \
    g2l16(kbase + (size_t)((kt_) * 64) * TRIPLE, Ks[buf_] + tid * 16);          \
    g2l16(kbase + (size_t)((kt_) * 64 + 32) * TRIPLE, Ks[buf_] + tid * 16 + 4096); \
    g2l16(vbase + (u32)((kt_) * 64), Vs[buf_] + tid * 16);                      \
    g2l16(vbase + (size_t)32 * T_SEQ + (u32)((kt_) * 64), Vs[buf_] + tid * 16 + 4096); \
  }

  char* Plb = Pl[w];

  const f32x4 zero = {0.f, 0.f, 0.f, 0.f};
  f32x4 o[4];
#pragma unroll
  for (int nt = 0; nt < 4; ++nt) o[nt] = zero;
  float mr = -INFINITY, lr = 0.f;
  short8 qa0 = qa2[0][0], qa1 = qa2[0][1];
  int q0 = q0A;

  // ---- prologue: stage tiles for i=0,1 into bufs 0,1; wait for buf 0 ----
  STAGE(0, 0);
  {
    const int kt1 = (1 <= p) ? 1 : 31;
    STAGE(kt1, 1);
  }
  asm volatile("s_waitcnt vmcnt(4)\n\ts_barrier" ::: "memory");

  int cur = 0;
  for (int i = 0;; ++i) {
    const int kt = (i <= p) ? i : 32 - i;

    // ---- 2-deep prefetch: stage tile for iteration i+2 ----
    if (i + 2 <= 32) {
      const int kt2 = (i + 2 <= p) ? i + 2 : 30 - i;
      int sb = cur - 1;
      if (sb < 0) sb = 2;
      STAGE(kt2, sb);
    }

    const int k0 = kt * 64;
    // wave-active guard: skip tiles entirely above this wave's q-band
    if (k0 <= q0 + w * 16) {
      // ---- S^T = K Q^T : lane holds S[key=mt*16+l4*4+r][q=l15] ----
      f32x4 s[4];
#pragma unroll
      for (int mt = 0; mt < 4; ++mt) s[mt] = zero;
      __builtin_amdgcn_s_setprio(1);
#pragma unroll
      for (int mt = 0; mt < 4; ++mt) {
        int row = mt * 16 + l15;
        int slot0 = l4 ^ (row & 7);
        short8 kb0 = *(const short8*)(Ks[cur] + row * 128 + slot0 * 16);
        s[mt] = __builtin_amdgcn_mfma_f32_16x16x32_bf16(kb0, qa0, s[mt], 0, 0, 0);
        int slot1 = (4 + l4) ^ (row & 7);
        short8 kb1 = *(const short8*)(Ks[cur] + row * 128 + slot1 * 16);
        s[mt] = __builtin_amdgcn_mfma_f32_16x16x32_bf16(kb1, qa1, s[mt], 0, 0, 0);
      }
      __builtin_amdgcn_s_setprio(0);

      // causal mask on the two diagonal iterations (A last, B first)
      if (i == p || i == p + 1) {
        const int qrow = q0 + w * 16 + l15;
#pragma unroll
        for (int mt = 0; mt < 4; ++mt)
#pragma unroll
          for (int r = 0; r < 4; ++r) {
            int key = k0 + mt * 16 + l4 * 4 + r;
            if (key > qrow) s[mt][r] = -INFINITY;
          }
      }

      // ---- online softmax, defer-max (THR = 8 in log2 units) ----
      float mx = fmaxf(fmaxf(fmaxf(s[0][0], s[0][1]), fmaxf(s[0][2], s[0][3])),
                       fmaxf(fmaxf(s[1][0], s[1][1]), fmaxf(s[1][2], s[1][3])));
      mx = fmaxf(mx, fmaxf(fmaxf(fmaxf(s[2][0], s[2][1]), fmaxf(s[2][2], s[2][3])),
                           fmaxf(fmaxf(s[3][0], s[3][1]), fmaxf(s[3][2], s[3][3]))));
      mx = fmaxf(mx, __shfl_xor(mx, 16));
      mx = fmaxf(mx, __shfl_xor(mx, 32));
      if (!__all(mx - mr <= 8.0f)) {
        float mn = fmaxf(mr, mx);
        float fr = exp2f(mr - mn);   // 0 on first active tile of a pass
        lr *= fr;
#pragma unroll
        for (int r = 0; r < 4; ++r) {
          float frq = __shfl(fr, l4 * 4 + r);
#pragma unroll
          for (int nt = 0; nt < 4; ++nt) o[nt][r] *= frq;
        }
        mr = mn;
      }
      float ps = 0.f;
#pragma unroll
      for (int mt = 0; mt < 4; ++mt)
#pragma unroll
        for (int r = 0; r < 4; ++r) {
          float pv = exp2f(s[mt][r] - mr);
          s[mt][r] = pv;
          ps += pv;
        }
      lr += ps;   // per-lane partial; reduced at pass epilogue

      // ---- P -> per-wave LDS (cvt_pk + b64 writes) ----
#pragma unroll
      for (int mt = 0; mt < 4; ++mt) {
        uint2 pw;
        pw.x = cvtpk(s[mt][0], s[mt][1]);
        pw.y = cvtpk(s[mt][2], s[mt][3]);
        int slot = ((mt * 2 + (l4 >> 1)) ^ (l15 & 7));
        *(uint2*)(Plb + l15 * 128 + (slot << 4) + ((l4 & 1) << 3)) = pw;
      }

      // ---- PV: o[q][d] += P[q][key] * V^T[d][key] ----
      __builtin_amdgcn_s_setprio(1);
#pragma unroll
      for (int kk = 0; kk < 2; ++kk) {
        short8 pa = *(const short8*)(Plb + l15 * 128 + (((kk * 4 + l4) ^ (l15 & 7)) << 4));
#pragma unroll
        for (int nt = 0; nt < 4; ++nt) {
          int d = nt * 16 + l15;
          int slot = (kk * 4 + l4) ^ (l15 & 7);
          short8 vb = *(const short8*)(Vs[cur] + d * 128 + slot * 16);
          o[nt] = __builtin_amdgcn_mfma_f32_16x16x32_bf16(pa, vb, o[nt], 0, 0, 0);
        }
      }
      __builtin_amdgcn_s_setprio(0);
    }

    // ---- pass epilogues (A diag: write+reset; final: write+exit) ----
    if (i == p || i == 32) {
      lr += __shfl_xor(lr, 16);
      lr += __shfl_xor(lr, 32);
#pragma unroll
      for (int r = 0; r < 4; ++r) {
        float lrq = __shfl(lr, l4 * 4 + r);
        float inv = __builtin_amdgcn_rcpf(lrq);
        size_t t = (size_t)(b * T_SEQ + q0 + w * 16 + l4 * 4 + r);
#pragma unroll
        for (int nt = 0; nt < 4; ++nt)
          ctx[t * DM + h * HD + nt * 16 + l15] = f2bf(o[nt][r] * inv);
      }
      if (i == 32) break;
      // reset for pass B (diag-first, descending)
#pragma unroll
      for (int nt = 0; nt < 4; ++nt) o[nt] = zero;
      mr = -INFINITY; lr = 0.f;
      qa0 = qa2[1][0]; qa1 = qa2[1][1];
      q0 = q0B;
    }

    // ---- counted-vmcnt barrier: newest stage (4 loads) stays in flight ----
    if (i == 31)
      asm volatile("s_waitcnt vmcnt(0)\n\ts_barrier" ::: "memory");
    else
      asm volatile("s_waitcnt vmcnt(4)\n\ts_barrier" ::: "memory");
    cur = (cur == 2) ? 0 : cur + 1;
  }
#undef STAGE
}

// ---------------------------------------------------------------------------
extern "C" void kernel_launch(void* const* d_in, const int* in_sizes, int n_in,
                              void* d_out, int out_size, void* d_ws, size_t ws_size,
                              hipStream_t stream) {
  const float* x = (const float*)d_in[0];
  const float* wqkv = (const float*)d_in[1];
  const float* wout = (const float*)d_in[2];
  float* out = (float*)d_out;
  char* ws = (char*)d_ws;

  u16* xb    = (u16*)(ws);                       //  8 MB
  u16* wqkvb = (u16*)(ws + 8u * 1024 * 1024);    //  6 MB
  u16* woutb = (u16*)(ws + 14u * 1024 * 1024);   //  2 MB
  u16* qkvb  = (u16*)(ws + 16u * 1024 * 1024);   // 24 MB
  u16* ctxb  = (u16*)(ws + 40u * 1024 * 1024);   //  8 MB
  u16* vTb   = (u16*)(ws + 48u * 1024 * 1024);   //  8 MB

  cast_all<<<8192, 256, 0, stream>>>((const float4*)x, (const float4*)wqkv,
                                     (const float4*)wout, (ushort4*)xb);

  gemm_bt<u16><<<dim3(24, 32), 256, 0, stream>>>(xb, wqkvb, qkvb, 4096, 3072, 1024);

  vtrans<<<dim3(8, N_H, N_B), 256, 0, stream>>>(qkvb, vTb);

  attn_fwd<<<dim3(32, 16), 256, 0, stream>>>(qkvb, vTb, ctxb);

  gemm_bt<float><<<dim3(8, 32), 256, 0, stream>>>(ctxb, woutb, out, 4096, 1024, 1024);
}

// Round 13
// 129.912 us; speedup vs baseline: 1.1657x; 1.0020x over previous
//
#include <hip/hip_runtime.h>

// ---------------------------------------------------------------------------
// MultiheadSelfAttention: x[2,2048,1024] f32, w_qkv[3072,1024] f32,
// w_out[1024,1024] f32 -> out[2,2048,1024] f32.
// cast->bf16; qkv = x @ w_qkv^T via 256x256 4-phase counted-vmcnt MFMA GEMM;
// V pre-transpose; causal flash attn (round-7 structure: 8-wave 128-row
// blocks, paired q-tiles, triple-buffered K/V, counted vmcnt, XCD-colocated);
// out = ctx @ w_out^T via 128x128 GEMM. fp32 accumulation.
// ---------------------------------------------------------------------------

typedef short short8 __attribute__((ext_vector_type(8)));
typedef float f32x4 __attribute__((ext_vector_type(4)));
typedef unsigned short u16;
typedef unsigned int u32;

#define T_SEQ 2048
#define N_B 2
#define N_H 16
#define HD 64
#define DM 1024
#define TRIPLE 3072

__device__ __forceinline__ u16 f2bf(float f) {
  union { float f; unsigned u; } v;
  v.f = f;
  unsigned r = v.u + 0x7fffu + ((v.u >> 16) & 1u);
  return (u16)(r >> 16);
}

__device__ __forceinline__ float bf2f(u16 x) {
  return __uint_as_float((u32)x << 16);
}

__device__ __forceinline__ u32 cvtpk(float a, float b) {
  u32 r;
  asm("v_cvt_pk_bf16_f32 %0, %1, %2" : "=v"(r) : "v"(a), "v"(b));
  return r;
}

typedef const __attribute__((address_space(1))) void gvoid;
typedef __attribute__((address_space(3))) void lvoid;

__device__ __forceinline__ void g2l16(const void* g, void* l) {
  __builtin_amdgcn_global_load_lds((gvoid*)g, (lvoid*)l, 16, 0, 0);
}

__device__ __forceinline__ void storeC(float* p, float v) { *p = v; }
__device__ __forceinline__ void storeC(u16* p, float v) { *p = f2bf(v); }

// ---------------------------------------------------------------------------
// fused cast of x | w_qkv | w_out into contiguous bf16 workspace
__global__ __launch_bounds__(256) void cast_all(const float4* __restrict__ x,
                                                const float4* __restrict__ wq,
                                                const float4* __restrict__ wo,
                                                ushort4* __restrict__ out) {
  int i = blockIdx.x * 256 + threadIdx.x;
  const float4* src;
  int off;
  if (i < 1048576) { src = x; off = 0; }
  else if (i < 1835008) { src = wq; off = 1048576; }
  else { src = wo; off = 1835008; }
  float4 v = src[i - off];
  ushort4 o;
  o.x = f2bf(v.x); o.y = f2bf(v.y); o.z = f2bf(v.z); o.w = f2bf(v.w);
  out[i] = o;
}

// ---------------------------------------------------------------------------
// V transpose: qkv[b*T+t][2048 + h*64 + d] -> vT[(b*16+h)*64 + d][t] (bf16).
// ---------------------------------------------------------------------------
__global__ __launch_bounds__(256) void vtrans(const u16* __restrict__ qkv,
                                              u16* __restrict__ vT) {
  const int tid = threadIdx.x;
  const int w = tid >> 6, lane = tid & 63;
  const int ti = lane >> 3, di = lane & 7;
  const int h = blockIdx.y, b = blockIdx.z;
  const int t0 = blockIdx.x * 256 + w * 64 + ti * 8;

  const u16* src = qkv + (size_t)(b * T_SEQ + t0) * TRIPLE + 2 * DM + h * HD + di * 8;
  u32 x[8][4];
#pragma unroll
  for (int e = 0; e < 8; ++e) {
    union { short8 v; u32 u[4]; } cv;
    cv.v = *(const short8*)(src + (size_t)e * TRIPLE);
#pragma unroll
    for (int j = 0; j < 4; ++j) x[e][j] = cv.u[j];
  }
  u32 y[8][4];
#pragma unroll
  for (int a = 0; a < 4; ++a)
#pragma unroll
    for (int j = 0; j < 4; ++j) {
      u32 lo = x[2 * a][j], hi = x[2 * a + 1][j];
      y[2 * a][j] = (lo & 0x0000FFFFu) | (hi << 16);
      y[2 * a + 1][j] = (lo >> 16) | (hi & 0xFFFF0000u);
    }
  u16* dst = vT + ((size_t)(b * N_H + h) * HD + di * 8) * T_SEQ + t0;
#pragma unroll
  for (int dd = 0; dd < 8; ++dd) {
    union { short8 v; u32 u[4]; } cv;
#pragma unroll
    for (int a = 0; a < 4; ++a) cv.u[a] = y[2 * a + (dd & 1)][dd >> 1];
    *(short8*)(dst + (size_t)dd * T_SEQ) = cv.v;
  }
}

// ---------------------------------------------------------------------------
// 256x256 tile, BK=64, 8 waves (2M x 4N), 4-phase inner loop with counted
// vmcnt barriers: C[M][N] = A[M][K] * W[N][K]^T (bf16 in, fp32 acc).
// Per iteration: 8 g2l16 prefetch (next K-tile), vmcnt(8)+barrier, then
// 4 phases x {8 ds_read_b128, lgkmcnt(0), 16 MFMA}, end barrier.
// ---------------------------------------------------------------------------
template <typename OutT>
__global__ __launch_bounds__(512, 2) void gemm_bt_256(const u16* __restrict__ A,
                                                      const u16* __restrict__ W,
                                                      OutT* __restrict__ C,
                                                      int M, int N, int K) {
  __shared__ char As[2][32768];   // [256 rows][8 slots x16B], slot = c^(row&7)
  __shared__ char Bs[2][32768];

  const int tid = threadIdx.x;
  const int lane = tid & 63, w = tid >> 6;
  const int l15 = lane & 15, l4 = lane >> 4;
  const int wm = w >> 2, wn = w & 3;          // 2 x 4 wave grid
  const int m0 = blockIdx.y * 256, n0 = blockIdx.x * 256;

  // staging bases: thread covers rows (tid>>3) + 64*r, fixed swizzled k-chunk
  const int srow = tid >> 3;
  const int sswz = ((tid & 7) ^ (srow & 7)) << 3;
  const u16* Abase = A + (size_t)(m0 + srow) * K + sswz;
  const u16* Bbase = W + (size_t)(n0 + srow) * K + sswz;

  const f32x4 zero = {0.f, 0.f, 0.f, 0.f};
  f32x4 acc[8][4];
#pragma unroll
  for (int am = 0; am < 8; ++am)
#pragma unroll
    for (int n = 0; n < 4; ++n) acc[am][n] = zero;

#define STAGE8(k0_, buf_)                                                      \
  {                                                                            \
    _Pragma("unroll") for (int r_ = 0; r_ < 4; ++r_) {                         \
      g2l16(Abase + (size_t)(64 * r_) * K + (k0_),                             \
            As[buf_] + (r_ * 512 + tid) * 16);                                 \
      g2l16(Bbase + (size_t)(64 * r_) * K + (k0_),                             \
            Bs[buf_] + (r_ * 512 + tid) * 16);                                 \
    }                                                                          \
  }

  // prologue: stage tile 0 into buf 0
  STAGE8(0, 0);

  const int nkt = K >> 6;
  for (int kt = 0;; ++kt) {
    const int cur = kt & 1;

    if (kt + 1 < nkt) {
      STAGE8((kt + 1) << 6, cur ^ 1);
      asm volatile("s_waitcnt vmcnt(8)" ::: "memory");
    } else {
      asm volatile("s_waitcnt vmcnt(0)" ::: "memory");
    }
    __builtin_amdgcn_s_barrier();   // buf[cur] visible to all waves

    // 4 phases: (kk = ph>>1, mh = ph&1); 16 independent MFMA per phase
#pragma unroll
    for (int ph = 0; ph < 4; ++ph) {
      const int kk = ph >> 1, mh = ph & 1;
      short8 a[4], b[4];
#pragma unroll
      for (int m = 0; m < 4; ++m) {
        int row = wm * 128 + mh * 64 + m * 16 + l15;
        int slot = (kk * 4 + l4) ^ (row & 7);
        a[m] = *(const short8*)(As[cur] + row * 128 + slot * 16);
      }
#pragma unroll
      for (int n = 0; n < 4; ++n) {
        int row = wn * 64 + n * 16 + l15;
        int slot = (kk * 4 + l4) ^ (row & 7);
        b[n] = *(const short8*)(Bs[cur] + row * 128 + slot * 16);
      }
      asm volatile("s_waitcnt lgkmcnt(0)" ::: "memory");
      __builtin_amdgcn_s_setprio(1);
#pragma unroll
      for (int m = 0; m < 4; ++m)
#pragma unroll
        for (int n = 0; n < 4; ++n)
          acc[mh * 4 + m][n] =
              __builtin_amdgcn_mfma_f32_16x16x32_bf16(a[m], b[n], acc[mh * 4 + m][n], 0, 0, 0);
      __builtin_amdgcn_s_setprio(0);
    }

    if (kt + 1 >= nkt) break;
    __builtin_amdgcn_s_barrier();   // all reads of buf[cur] done before reuse
  }
#undef STAGE8

  // epilogue
#pragma unroll
  for (int am = 0; am < 8; ++am)
#pragma unroll
    for (int n = 0; n < 4; ++n)
#pragma unroll
      for (int r = 0; r < 4; ++r) {
        int row = m0 + wm * 128 + (am >> 2) * 64 + (am & 3) * 16 + l4 * 4 + r;
        int col = n0 + wn * 64 + n * 16 + l15;
        storeC(C + (size_t)row * N + col, acc[am][n][r]);
      }
}

// ---------------------------------------------------------------------------
// 128x128 tile GEMM (m97 structure) — used for the output projection.
// ---------------------------------------------------------------------------
template <typename OutT>
__global__ __launch_bounds__(256) void gemm_bt(const u16* __restrict__ A,
                                               const u16* __restrict__ W,
                                               OutT* __restrict__ C,
                                               int M, int N, int K) {
  __shared__ char As[128 * 64 * 2];
  __shared__ char Bs[128 * 64 * 2];
  const int tid = threadIdx.x;
  const int lane = tid & 63, w = tid >> 6;
  const int l15 = lane & 15, l4 = lane >> 4;
  const int m0 = blockIdx.y * 128, n0 = blockIdx.x * 128;
  const int wr = (w >> 1) * 64, wc = (w & 1) * 64;

  const f32x4 zero = {0.f, 0.f, 0.f, 0.f};
  f32x4 acc[4][4];
#pragma unroll
  for (int m = 0; m < 4; ++m)
#pragma unroll
    for (int n = 0; n < 4; ++n) acc[m][n] = zero;

  for (int k0 = 0; k0 < K; k0 += 64) {
#pragma unroll
    for (int i = 0; i < 4; ++i) {
      const int cb = (i * 4 + w) * 64;
      const int c = cb + lane;
      const int row = c >> 3;
      const int ks = ((c & 7) ^ (row & 7)) * 8;
      g2l16(A + (size_t)(m0 + row) * K + k0 + ks, As + (size_t)cb * 16);
      g2l16(W + (size_t)(n0 + row) * K + k0 + ks, Bs + (size_t)cb * 16);
    }
    __syncthreads();

#pragma unroll
    for (int kk = 0; kk < 2; ++kk) {
      short8 a[4], b[4];
#pragma unroll
      for (int m = 0; m < 4; ++m) {
        int row = wr + m * 16 + l15;
        int slot = (kk * 4 + l4) ^ (row & 7);
        a[m] = *(const short8*)(As + row * 128 + slot * 16);
      }
#pragma unroll
      for (int n = 0; n < 4; ++n) {
        int row = wc + n * 16 + l15;
        int slot = (kk * 4 + l4) ^ (row & 7);
        b[n] = *(const short8*)(Bs + row * 128 + slot * 16);
      }
#pragma unroll
      for (int m = 0; m < 4; ++m)
#pragma unroll
        for (int n = 0; n < 4; ++n)
          acc[m][n] = __builtin_amdgcn_mfma_f32_16x16x32_bf16(a[m], b[n], acc[m][n], 0, 0, 0);
    }
    __syncthreads();
  }

#pragma unroll
  for (int m = 0; m < 4; ++m)
#pragma unroll
    for (int n = 0; n < 4; ++n)
#pragma unroll
      for (int r = 0; r < 4; ++r) {
        int row = m0 + wr + m * 16 + l4 * 4 + r;
        int col = n0 + wc + n * 16 + l15;
        storeC(C + (size_t)row * N + col, acc[m][n][r]);
      }
}

// ---------------------------------------------------------------------------
// Causal flash attention (round-7 structure, best measured). 8-wave blocks,
// 128 q-rows per pass, paired q-tiles (p, 15-p). Pass A: kt = 0..2p+1
// ascending (diag last). Pass B: kt = 31-2p..0 descending (diag first).
// 34 iterations for every block. Triple-buffered K/V staged by
// global_load_lds with 2-deep prefetch; barriers use counted vmcnt(2).
// Grid: x = (b,h) group (XCD colocation), y = p.
// ---------------------------------------------------------------------------
__global__ __launch_bounds__(512) void attn_fwd(const u16* __restrict__ qkv,
                                                const u16* __restrict__ vT,
                                                u16* __restrict__ ctx) {
  __shared__ char Ks[3][8192];   // K tile [64 key][8 slots x 16B], slot=c^(row&7)
  __shared__ char Vs[3][8192];   // V^T tile [64 d][8 slots x 16B], slot=c^(d&7)
  __shared__ char Pl[8][2048];   // per-wave P [16 q][64 key], swizzled

  const int tid = threadIdx.x;
  const int lane = tid & 63, w = tid >> 6;        // w in 0..7
  const int l15 = lane & 15, l4 = lane >> 4;
  const int g = blockIdx.x;                       // b*16+h : same-XCD group
  const int p = blockIdx.y;                       // 0..7
  const int h = g & 15, b = g >> 4;
  const int q0A = 128 * p, q0B = 128 * (15 - p);
  const int nA = 2 * p + 2;                       // pass-A iterations; total 34

  // ---- preload Q for BOTH passes, prescaled by 0.125*log2(e) ----
  const float c_log2 = 0.18033688011112042f;
  short8 qa2[2][2];
#pragma unroll
  for (int ps = 0; ps < 2; ++ps) {
    const int qq0 = ps ? q0B : q0A;
    const u16* qp = qkv + (size_t)(b * T_SEQ + qq0 + w * 16 + l15) * TRIPLE + h * HD;
#pragma unroll
    for (int kk = 0; kk < 2; ++kk) {
      short8 raw = *(const short8*)(qp + kk * 32 + l4 * 8);
      union { short8 v; u32 w4[4]; } qq;
#pragma unroll
      for (int j = 0; j < 4; ++j)
        qq.w4[j] = cvtpk(bf2f((u16)raw[2 * j]) * c_log2,
                         bf2f((u16)raw[2 * j + 1]) * c_log2);
      qa2[ps][kk] = qq.v;
    }
  }

  // ---- staging bases (pre-swizzled source, linear LDS dest) ----
  const int r0 = tid >> 3, c0 = tid & 7;          // r0: 0..63 (512 threads)
  const int swz = (c0 ^ (r0 & 7)) << 3;
  const u16* kbase = qkv + (size_t)(b * T_SEQ + r0) * TRIPLE + DM + h * HD + swz;
  const u16* vbase = vT + ((size_t)g * HD + r0) * T_SEQ + swz;

#define STAGE(kt_, buf_)                                                     \
  {                                                                          \
    g2l16(kbase + (size_t)((kt_) * (64 * TRIPLE)), Ks[buf_] + tid * 16);     \
    g2l16(vbase + (u32)((kt_) * 64), Vs[buf_] + tid * 16);                   \
  }

  char* Plb = Pl[w];

  const f32x4 zero = {0.f, 0.f, 0.f, 0.f};
  f32x4 o[4];
#pragma unroll
  for (int nt = 0; nt < 4; ++nt) o[nt] = zero;
  float mr = -INFINITY, lr = 0.f;
  short8 qa0 = qa2[0][0], qa1 = qa2[0][1];
  int q0 = q0A;

  // ---- prologue: stage seq 0,1 into bufs 0,1; wait seq0 only ----
  STAGE(0, 0);
  STAGE(1, 1);
  asm volatile("s_waitcnt vmcnt(2)\n\ts_barrier" ::: "memory");

  int cur = 0;
  for (int i = 0;; ++i) {
    const int kt = (i < nA) ? i : 33 - i;

    // ---- issue 2-ahead prefetch into buf (cur+2)%3 ----
    if (i + 2 < 34) {
      const int kt2 = (i + 2 < nA) ? (i + 2) : 31 - i;
      int sb = cur - 1;
      if (sb < 0) sb = 2;
      STAGE(kt2, sb);
    }

    const int k0 = kt * 64;
    // wave-active guard: skip tiles entirely above this wave's q-band
    if (k0 <= q0 + w * 16) {
      // ---- S^T = K Q^T : lane holds S[key=mt*16+l4*4+r][q=l15] ----
      f32x4 s[4];
#pragma unroll
      for (int mt = 0; mt < 4; ++mt) s[mt] = zero;
      __builtin_amdgcn_s_setprio(1);
#pragma unroll
      for (int mt = 0; mt < 4; ++mt) {
        int row = mt * 16 + l15;
        int slot0 = l4 ^ (row & 7);
        short8 kb0 = *(const short8*)(Ks[cur] + row * 128 + slot0 * 16);
        s[mt] = __builtin_amdgcn_mfma_f32_16x16x32_bf16(kb0, qa0, s[mt], 0, 0, 0);
        int slot1 = (4 + l4) ^ (row & 7);
        short8 kb1 = *(const short8*)(Ks[cur] + row * 128 + slot1 * 16);
        s[mt] = __builtin_amdgcn_mfma_f32_16x16x32_bf16(kb1, qa1, s[mt], 0, 0, 0);
      }
      __builtin_amdgcn_s_setprio(0);

      // causal mask near the diagonal (Q pre-scaled; S in log2 units)
      if (i >= nA - 2 && i <= nA + 1) {
        const int qrow = q0 + w * 16 + l15;
#pragma unroll
        for (int mt = 0; mt < 4; ++mt)
#pragma unroll
          for (int r = 0; r < 4; ++r) {
            int key = k0 + mt * 16 + l4 * 4 + r;
            if (key > qrow) s[mt][r] = -INFINITY;
          }
      }

      // ---- online softmax, defer-max (THR = 8 in log2 units) ----
      float mx = fmaxf(fmaxf(fmaxf(s[0][0], s[0][1]), fmaxf(s[0][2], s[0][3])),
                       fmaxf(fmaxf(s[1][0], s[1][1]), fmaxf(s[1][2], s[1][3])));
      mx = fmaxf(mx, fmaxf(fmaxf(fmaxf(s[2][0], s[2][1]), fmaxf(s[2][2], s[2][3])),
                           fmaxf(fmaxf(s[3][0], s[3][1]), fmaxf(s[3][2], s[3][3]))));
      mx = fmaxf(mx, __shfl_xor(mx, 16));
      mx = fmaxf(mx, __shfl_xor(mx, 32));
      if (!__all(mx - mr <= 8.0f)) {
        float mn = fmaxf(mr, mx);
        float fr = exp2f(mr - mn);   // 0 on first active tile of a pass
        lr *= fr;
#pragma unroll
        for (int r = 0; r < 4; ++r) {
          float frq = __shfl(fr, l4 * 4 + r);
#pragma unroll
          for (int nt = 0; nt < 4; ++nt) o[nt][r] *= frq;
        }
        mr = mn;
      }
      float ps = 0.f;
#pragma unroll
      for (int mt = 0; mt < 4; ++mt)
#pragma unroll
        for (int r = 0; r < 4; ++r) {
          float pv = exp2f(s[mt][r] - mr);
          s[mt][r] = pv;
          ps += pv;
        }
      lr += ps;   // per-lane partial; reduced at pass epilogue

      // ---- P -> per-wave LDS (cvt_pk + b64 writes) ----
#pragma unroll
      for (int mt = 0; mt < 4; ++mt) {
        uint2 pw;
        pw.x = cvtpk(s[mt][0], s[mt][1]);
        pw.y = cvtpk(s[mt][2], s[mt][3]);
        int slot = ((mt * 2 + (l4 >> 1)) ^ (l15 & 7));
        *(uint2*)(Plb + l15 * 128 + (slot << 4) + ((l4 & 1) << 3)) = pw;
      }

      // ---- PV: o[q][d] += P[q][key] * V^T[d][key] ----
      __builtin_amdgcn_s_setprio(1);
#pragma unroll
      for (int kk = 0; kk < 2; ++kk) {
        short8 pa = *(const short8*)(Plb + l15 * 128 + (((kk * 4 + l4) ^ (l15 & 7)) << 4));
#pragma unroll
        for (int nt = 0; nt < 4; ++nt) {
          int d = nt * 16 + l15;
          int slot = (kk * 4 + l4) ^ (l15 & 7);
          short8 vb = *(const short8*)(Vs[cur] + d * 128 + slot * 16);
          o[nt] = __builtin_amdgcn_mfma_f32_16x16x32_bf16(pa, vb, o[nt], 0, 0, 0);
        }
      }
      __builtin_amdgcn_s_setprio(0);
    }

    // ---- pass epilogues ----
    if (i == nA - 1 || i == 33) {
      lr += __shfl_xor(lr, 16);
      lr += __shfl_xor(lr, 32);
#pragma unroll
      for (int r = 0; r < 4; ++r) {
        float lrq = __shfl(lr, l4 * 4 + r);
        float inv = __builtin_amdgcn_rcpf(lrq);
        size_t t = (size_t)(b * T_SEQ + q0 + w * 16 + l4 * 4 + r);
#pragma unroll
        for (int nt = 0; nt < 4; ++nt)
          ctx[t * DM + h * HD + nt * 16 + l15] = f2bf(o[nt][r] * inv);
      }
      if (i == 33) break;
      // reset for pass B
#pragma unroll
      for (int nt = 0; nt < 4; ++nt) o[nt] = zero;
      mr = -INFINITY; lr = 0.f;
      qa0 = qa2[1][0]; qa1 = qa2[1][1];
      q0 = q0B;
    }

    // ---- counted-vmcnt barrier: keep newest stage (2 loads) in flight ----
    if (i == 32)
      asm volatile("s_waitcnt vmcnt(0)\n\ts_barrier" ::: "memory");
    else
      asm volatile("s_waitcnt vmcnt(2)\n\ts_barrier" ::: "memory");
    cur = (cur == 2) ? 0 : cur + 1;
  }
#undef STAGE
}

// ---------------------------------------------------------------------------
extern "C" void kernel_launch(void* const* d_in, const int* in_sizes, int n_in,
                              void* d_out, int out_size, void* d_ws, size_t ws_size,
                              hipStream_t stream) {
  const float* x = (const float*)d_in[0];
  const float* wqkv = (const float*)d_in[1];
  const float* wout = (const float*)d_in[2];
  float* out = (float*)d_out;
  char* ws = (char*)d_ws;

  u16* xb    = (u16*)(ws);                       //  8 MB
  u16* wqkvb = (u16*)(ws + 8u * 1024 * 1024);    //  6 MB
  u16* woutb = (u16*)(ws + 14u * 1024 * 1024);   //  2 MB
  u16* qkvb  = (u16*)(ws + 16u * 1024 * 1024);   // 24 MB
  u16* ctxb  = (u16*)(ws + 40u * 1024 * 1024);   //  8 MB
  u16* vTb   = (u16*)(ws + 48u * 1024 * 1024);   //  8 MB

  cast_all<<<8192, 256, 0, stream>>>((const float4*)x, (const float4*)wqkv,
                                     (const float4*)wout, (ushort4*)xb);

  // qkv[4096][3072] = xb @ wqkvb^T : 256x256 4-phase kernel, grid 12x16
  gemm_bt_256<u16><<<dim3(12, 16), 512, 0, stream>>>(xb, wqkvb, qkvb, 4096, 3072, 1024);

  vtrans<<<dim3(8, N_H, N_B), 256, 0, stream>>>(qkvb, vTb);

  attn_fwd<<<dim3(32, 8), 512, 0, stream>>>(qkvb, vTb, ctxb);

  gemm_bt<float><<<dim3(8, 32), 256, 0, stream>>>(ctxb, woutb, out, 4096, 1024, 1024);
}